// Round 23
// baseline (128.489 us; speedup 1.0000x reference)
//
#include <hip/hip_runtime.h>

typedef float f32x4 __attribute__((ext_vector_type(4)));
typedef unsigned long long ull;

#define OFF_PRED 26214400      // 32*128*128*50
#define OFF_XU   56934400      // OFF_PRED + 32*64*300*50
#define LROW 328               // fp8 LDS row stride bytes: 320 + 8 pad
#define BUFSZ (64 * LROW)      // 20992 B per X-tile

// pack 4 floats into 4 fp8 e4m3 bytes (one u32)
__device__ inline unsigned pack4_fp8(float a, float b, float c, float d) {
    int r = __builtin_amdgcn_cvt_pk_fp8_f32(a, b, 0, false);   // bytes 0,1
    r = __builtin_amdgcn_cvt_pk_fp8_f32(c, d, r, true);        // bytes 2,3
    return (unsigned)r;
}

// ---- K0: build M in MFMA-fragment order, fp8.
// Logical M[640][320]: rows 0..255 = C, 256..555 = A, rest 0; cols k<300 real, else 0.
// frag elem byte = ((mt*10+ks)*64 + lane)*8 + e ; m = mt*16+(lane&15), k = ks*32+(lane>>4)*8+e.
__global__ void build_M(const float* __restrict__ A, const float* __restrict__ C,
                        unsigned* __restrict__ M) {
    int idx = blockIdx.x * 256 + threadIdx.x;      // u32 index (4 fp8 elems)
    if (idx >= 51200) return;                      // 640*320/4
    int d = idx * 4;
    int e0 = d & 7, lane = (d >> 3) & 63, fs = d >> 9;
    int mt = fs / 10, ks = fs % 10;
    int m = mt * 16 + (lane & 15);
    int k = ks * 32 + (lane >> 4) * 8 + e0;
    float f0 = 0.f, f1 = 0.f, f2 = 0.f, f3 = 0.f;
    const float* src = nullptr;
    if (m < 256) src = C + m * 300;
    else if (m < 556) src = A + (m - 256) * 300;
    if (src) {
        if (k + 0 < 300) f0 = src[k + 0];
        if (k + 1 < 300) f1 = src[k + 1];
        if (k + 2 < 300) f2 = src[k + 2];
        if (k + 3 < 300) f3 = src[k + 3];
    }
    M[idx] = pack4_fp8(f0, f1, f2, f3);
}

// ---- K1: R22 structure + fused XU tail. Block (bpp, mhalf) serves bp0 = 2bpp, bp1 = 2bpp+1.
//      After the epilogue (acc/M dead), blocks with raw bid < 1875 each compute 256
//      elements of X_U — overlaps the old serial xu kernel with other blocks' gemm phases.
__global__ __launch_bounds__(256, 2) void gemm_main(
    const float* __restrict__ X, const float* __restrict__ x0,
    const char* __restrict__ M, const float* __restrict__ U,
    const float* __restrict__ Bm, float* __restrict__ out)
{
    __shared__ char ldsb[2 * BUFSZ];               // 41984 B
    const int sw = ((blockIdx.x & 7) << 8) + (blockIdx.x >> 3);
    const int bpp = sw >> 1, mhalf = sw & 1;
    const int bp0 = bpp * 2;
    const int tid = threadIdx.x;

    const int wave = tid >> 6, lane = tid & 63;
    const int lr = lane & 15, lg = lane >> 4;
    const int g = wave;

    // B-frag base (fp8 frag-ordered M): mt = (mhalf*4+g)*5 + j, frag (mt,ks) = 512B burst
    const char* Mw = M + ((mhalf * 4 + g) * 5 * 10) * 512 + lane * 8;

    // prefetch ks=0 B-frags (fly during staging)
    long long pf[5];
    #pragma unroll
    for (int j = 0; j < 5; j++) pf[j] = *(const long long*)(Mw + (j * 10) * 512);

    // ---- staging: pad-zero + x0 + X for BOTH tiles, disjoint bytes, ONE barrier ----
    // (a) pad cols [300,328) of rows 0..50: 51*7 = 357 u32 per tile
    #pragma unroll
    for (int u = 0; u < 2; u++) {
        int i = tid + u * 256;
        if (i < 357) {
            int row = i / 7, c = i % 7;
            *(unsigned*)(ldsb + row * LROW + 300 + c * 4) = 0u;
            *(unsigned*)(ldsb + BUFSZ + row * LROW + 300 + c * 4) = 0u;
        }
    }
    // (b) rows 51..63 fully zero: 13*328/8 = 533 ull per tile (51*328 = 16728, 8-aligned)
    #pragma unroll
    for (int u = 0; u < 3; u++) {
        int i = tid + u * 256;
        if (i < 533) {
            *(ull*)(ldsb + 16728 + i * 8) = 0ULL;
            *(ull*)(ldsb + BUFSZ + 16728 + i * 8) = 0ULL;
        }
    }
    // (c) x0 -> row 0 of each tile
    if (tid < 150) {
        int tau = tid / 75, c = tid - tau * 75;
        f32x4 v = *(const f32x4*)(x0 + (bp0 + tau) * 300 + c * 4);
        *(unsigned*)(ldsb + tau * BUFSZ + c * 4) = pack4_fp8(v.x, v.y, v.z, v.w);
    }
    // (d) X -> rows 1..50 (transposed), aligned float2 t-pairs; 2*1875 items
    #pragma unroll
    for (int u = 0; u < 15; u++) {
        int i = tid + u * 256;
        if (i < 3750) {
            int tau = i / 1875, rem = i - tau * 1875;
            int tp = rem % 25, jq = rem / 25;
            const float* s = X + (bp0 + tau) * 15000 + jq * 200 + tp * 2;
            float2 v0 = *(const float2*)(s);
            float2 v1 = *(const float2*)(s + 50);
            float2 v2 = *(const float2*)(s + 100);
            float2 v3 = *(const float2*)(s + 150);
            char* lb = ldsb + tau * BUFSZ;
            *(unsigned*)(lb + (tp * 2 + 1) * LROW + jq * 4) = pack4_fp8(v0.x, v1.x, v2.x, v3.x);
            *(unsigned*)(lb + (tp * 2 + 2) * LROW + jq * 4) = pack4_fp8(v0.y, v1.y, v2.y, v3.y);
        }
    }
    __syncthreads();

    f32x4 acc0[5][4], acc1[5][4];
    #pragma unroll
    for (int j = 0; j < 5; j++)
        #pragma unroll
        for (int nt = 0; nt < 4; nt++) {
            acc0[j][nt] = (f32x4){0.f, 0.f, 0.f, 0.f};
            acc1[j][nt] = (f32x4){0.f, 0.f, 0.f, 0.f};
        }

    // A-frag: tile base TB, row = nt*16 + lr, 8B at k-bytes ks*32 + lg*8
    #define LDSA(TB, nt, ks) (*(const long long*)(ldsb + (TB) + ((nt) * 16 + lr) * LROW + \
                             (ks) * 32 + lg * 8))

    #pragma unroll
    for (int ks = 0; ks < 10; ks++) {
        long long bf0, bf1, bf2, bf3, bf4;
        if (ks == 0) {
            bf0 = pf[0]; bf1 = pf[1]; bf2 = pf[2]; bf3 = pf[3]; bf4 = pf[4];
        } else {
            bf0 = *(const long long*)(Mw + (0 * 10 + ks) * 512);
            bf1 = *(const long long*)(Mw + (1 * 10 + ks) * 512);
            bf2 = *(const long long*)(Mw + (2 * 10 + ks) * 512);
            bf3 = *(const long long*)(Mw + (3 * 10 + ks) * 512);
            bf4 = *(const long long*)(Mw + (4 * 10 + ks) * 512);
        }
        #pragma unroll
        for (int nt = 0; nt < 4; nt++) {
            long long a = LDSA(0, nt, ks);
            acc0[0][nt] = __builtin_amdgcn_mfma_f32_16x16x32_fp8_fp8(a, bf0, acc0[0][nt], 0, 0, 0);
            acc0[1][nt] = __builtin_amdgcn_mfma_f32_16x16x32_fp8_fp8(a, bf1, acc0[1][nt], 0, 0, 0);
            acc0[2][nt] = __builtin_amdgcn_mfma_f32_16x16x32_fp8_fp8(a, bf2, acc0[2][nt], 0, 0, 0);
            acc0[3][nt] = __builtin_amdgcn_mfma_f32_16x16x32_fp8_fp8(a, bf3, acc0[3][nt], 0, 0, 0);
            acc0[4][nt] = __builtin_amdgcn_mfma_f32_16x16x32_fp8_fp8(a, bf4, acc0[4][nt], 0, 0, 0);
        }
        #pragma unroll
        for (int nt = 0; nt < 4; nt++) {
            long long a = LDSA(BUFSZ, nt, ks);
            acc1[0][nt] = __builtin_amdgcn_mfma_f32_16x16x32_fp8_fp8(a, bf0, acc1[0][nt], 0, 0, 0);
            acc1[1][nt] = __builtin_amdgcn_mfma_f32_16x16x32_fp8_fp8(a, bf1, acc1[1][nt], 0, 0, 0);
            acc1[2][nt] = __builtin_amdgcn_mfma_f32_16x16x32_fp8_fp8(a, bf2, acc1[2][nt], 0, 0, 0);
            acc1[3][nt] = __builtin_amdgcn_mfma_f32_16x16x32_fp8_fp8(a, bf3, acc1[3][nt], 0, 0, 0);
            acc1[4][nt] = __builtin_amdgcn_mfma_f32_16x16x32_fp8_fp8(a, bf4, acc1[4][nt], 0, 0, 0);
        }
    }
    #undef LDSA

    // ---- epilogue: col m = mhalf*320 + g*80 + j*16 + lr, ext-col n = nt*16 + lg*4 + q ----
#define EPILOGUE(ACC, BP) { \
    const int b_ = (BP) >> 6, p_ = (BP) & 63; \
    const int gr_ = p_ >> 3, gc_ = p_ & 7; \
    _Pragma("unroll") \
    for (int j = 0; j < 5; j++) { \
        int colm = mhalf * 320 + g * 80 + j * 16 + lr; \
        if (colm < 256) { \
            int base = b_ * 819200 + ((gr_ * 16 + (colm >> 4)) * 128 + gc_ * 16 + (colm & 15)) * 50; \
            _Pragma("unroll") \
            for (int nt = 0; nt < 4; nt++) { \
                int t0 = nt * 16 + lg * 4; \
                if (t0 == 0) { \
                    out[base + 0] = ACC[j][0][1]; \
                    out[base + 1] = ACC[j][0][2]; \
                    out[base + 2] = ACC[j][0][3]; \
                } else if (t0 <= 46) { \
                    f32x4 v = ACC[j][nt]; \
                    __builtin_memcpy(&out[base + t0 - 1], &v, 16); \
                } else if (t0 == 48) { \
                    out[base + 47] = ACC[j][nt][0]; \
                    out[base + 48] = ACC[j][nt][1]; \
                    out[base + 49] = ACC[j][nt][2]; \
                } \
            } \
        } else if (colm < 556) { \
            int base = OFF_PRED + ((BP) * 300 + (colm - 256)) * 50; \
            _Pragma("unroll") \
            for (int nt = 0; nt < 4; nt++) { \
                int t0 = nt * 16 + lg * 4; \
                if (t0 <= 46) { \
                    f32x4 v = ACC[j][nt]; \
                    __builtin_memcpy(&out[base + t0], &v, 16); \
                } else if (t0 == 48) { \
                    out[base + 48] = ACC[j][nt][0]; \
                    out[base + 49] = ACC[j][nt][1]; \
                } \
            } \
        } \
    } }

    EPILOGUE(acc0, bp0);
    EPILOGUE(acc1, bp0 + 1);
#undef EPILOGUE

    // ---- fused XU tail: raw-bid partition (blocks 0..1874), 1 element/thread.
    //      X_U[b,i,t] = 0.5*(1+exp(-(B·U)[b,i,t])) * sum_p |X[b,p,i,t]|.
    //      Runs after epilogue (acc/M dead); overlaps other blocks' gemm phases.
    {
        int id = blockIdx.x * 256 + tid;
        if (id < 480000) {
            int t = id % 50;
            int i = (id / 50) % 300;
            int b_ = id / 15000;
            const float* xp = X + b_ * 960000 + i * 50 + t;
            float s = 0.f;
            #pragma unroll 8
            for (int pp = 0; pp < 64; pp++) s += fabsf(xp[pp * 15000]);
            float bu = 0.f;
            const float* up = U + b_ * 2000 + t;
            const float* Bp = Bm + i * 40;
            #pragma unroll 8
            for (int q = 0; q < 40; q++) bu += Bp[q] * up[q * 50];
            out[OFF_XU + id] = 0.5f * (1.f + expf(-bu)) * s;
        }
    }
}

extern "C" void kernel_launch(void* const* d_in, const int* in_sizes, int n_in,
                              void* d_out, int out_size, void* d_ws, size_t ws_size,
                              hipStream_t stream) {
    const float* X  = (const float*)d_in[0];
    const float* U  = (const float*)d_in[1];
    const float* x0 = (const float*)d_in[2];
    const float* A  = (const float*)d_in[3];
    const float* B  = (const float*)d_in[4];
    const float* C  = (const float*)d_in[5];
    float* out = (float*)d_out;
    unsigned* M = (unsigned*)d_ws;      // 640*320 fp8 = 204,800 B (fragment-ordered)

    build_M<<<200, 256, 0, stream>>>(A, C, M);
    gemm_main<<<2048, 256, 0, stream>>>(X, x0, (const char*)M, U, B, out);
}

// Round 24
// 118.809 us; speedup vs baseline: 1.0815x; 1.0815x over previous
//
#include <hip/hip_runtime.h>

typedef float f32x4 __attribute__((ext_vector_type(4)));
typedef unsigned long long ull;

#define OFF_PRED 26214400      // 32*128*128*50
#define OFF_XU   56934400      // OFF_PRED + 32*64*300*50
#define LROW 328               // fp8 LDS row stride bytes: 320 + 8 pad
#define BUFSZ (64 * LROW)      // 20992 B per X-tile

// pack 4 floats into 4 fp8 e4m3 bytes (one u32)
__device__ inline unsigned pack4_fp8(float a, float b, float c, float d) {
    int r = __builtin_amdgcn_cvt_pk_fp8_f32(a, b, 0, false);   // bytes 0,1
    r = __builtin_amdgcn_cvt_pk_fp8_f32(c, d, r, true);        // bytes 2,3
    return (unsigned)r;
}

// ---- K0: build M in MFMA-fragment order, fp8.
// Logical M[640][320]: rows 0..255 = C, 256..555 = A, rest 0; cols k<300 real, else 0.
// frag elem byte = ((mt*10+ks)*64 + lane)*8 + e ; m = mt*16+(lane&15), k = ks*32+(lane>>4)*8+e.
__global__ void build_M(const float* __restrict__ A, const float* __restrict__ C,
                        unsigned* __restrict__ M) {
    int idx = blockIdx.x * 256 + threadIdx.x;      // u32 index (4 fp8 elems)
    if (idx >= 51200) return;                      // 640*320/4
    int d = idx * 4;
    int e0 = d & 7, lane = (d >> 3) & 63, fs = d >> 9;
    int mt = fs / 10, ks = fs % 10;
    int m = mt * 16 + (lane & 15);
    int k = ks * 32 + (lane >> 4) * 8 + e0;
    float f0 = 0.f, f1 = 0.f, f2 = 0.f, f3 = 0.f;
    const float* src = nullptr;
    if (m < 256) src = C + m * 300;
    else if (m < 556) src = A + (m - 256) * 300;
    if (src) {
        if (k + 0 < 300) f0 = src[k + 0];
        if (k + 1 < 300) f1 = src[k + 1];
        if (k + 2 < 300) f2 = src[k + 2];
        if (k + 3 < 300) f3 = src[k + 3];
    }
    M[idx] = pack4_fp8(f0, f1, f2, f3);
}

// ---- K1: R22 gemm (bid < 2048) + TRAILING XU blocks (bid >= 2048).
//      xu blocks dispatch only as gemm blocks retire -> they fill freed CU slots
//      and overlap the still-running gemm blocks (no displacement, no tail-extension).
__global__ __launch_bounds__(256, 2) void gemm_main(
    const float* __restrict__ X, const float* __restrict__ x0,
    const char* __restrict__ M, const float* __restrict__ U,
    const float* __restrict__ Bm, float* __restrict__ out)
{
    __shared__ char ldsb[2 * BUFSZ];               // 41984 B
    const int tid = threadIdx.x;

    if (blockIdx.x >= 2048) {
        // ---------------- XU role: X_U[b,i,t] = 0.5*(1+exp(-(B·U))) * sum_p |X| ------
        int id = (blockIdx.x - 2048) * 256 + tid;
        if (id >= 480000) return;
        int t = id % 50;
        int i = (id / 50) % 300;
        int b_ = id / 15000;
        const float* xp = X + b_ * 960000 + i * 50 + t;
        float s = 0.f;
        #pragma unroll 8
        for (int pp = 0; pp < 64; pp++) s += fabsf(xp[pp * 15000]);
        float bu = 0.f;
        const float* up = U + b_ * 2000 + t;
        const float* Bp = Bm + i * 40;
        #pragma unroll 8
        for (int q = 0; q < 40; q++) bu += Bp[q] * up[q * 50];
        out[OFF_XU + id] = 0.5f * (1.f + expf(-bu)) * s;
        return;
    }

    // ---------------- GEMM role (R22-identical) ----------------
    const int sw = ((blockIdx.x & 7) << 8) + (blockIdx.x >> 3);   // 2048 = 8*256, bijective
    const int bpp = sw >> 1, mhalf = sw & 1;
    const int bp0 = bpp * 2;

    const int wave = tid >> 6, lane = tid & 63;
    const int lr = lane & 15, lg = lane >> 4;
    const int g = wave;

    // B-frag base (fp8 frag-ordered M): mt = (mhalf*4+g)*5 + j, frag (mt,ks) = 512B burst
    const char* Mw = M + ((mhalf * 4 + g) * 5 * 10) * 512 + lane * 8;

    // prefetch ks=0 B-frags (fly during staging)
    long long pf[5];
    #pragma unroll
    for (int j = 0; j < 5; j++) pf[j] = *(const long long*)(Mw + (j * 10) * 512);

    // ---- staging: pad-zero + x0 + X for BOTH tiles, disjoint bytes, ONE barrier ----
    // (a) pad cols [300,328) of rows 0..50: 51*7 = 357 u32 per tile
    #pragma unroll
    for (int u = 0; u < 2; u++) {
        int i = tid + u * 256;
        if (i < 357) {
            int row = i / 7, c = i % 7;
            *(unsigned*)(ldsb + row * LROW + 300 + c * 4) = 0u;
            *(unsigned*)(ldsb + BUFSZ + row * LROW + 300 + c * 4) = 0u;
        }
    }
    // (b) rows 51..63 fully zero: 13*328/8 = 533 ull per tile (51*328 = 16728, 8-aligned)
    #pragma unroll
    for (int u = 0; u < 3; u++) {
        int i = tid + u * 256;
        if (i < 533) {
            *(ull*)(ldsb + 16728 + i * 8) = 0ULL;
            *(ull*)(ldsb + BUFSZ + 16728 + i * 8) = 0ULL;
        }
    }
    // (c) x0 -> row 0 of each tile
    if (tid < 150) {
        int tau = tid / 75, c = tid - tau * 75;
        f32x4 v = *(const f32x4*)(x0 + (bp0 + tau) * 300 + c * 4);
        *(unsigned*)(ldsb + tau * BUFSZ + c * 4) = pack4_fp8(v.x, v.y, v.z, v.w);
    }
    // (d) X -> rows 1..50 (transposed), aligned float2 t-pairs; 2*1875 items
    #pragma unroll
    for (int u = 0; u < 15; u++) {
        int i = tid + u * 256;
        if (i < 3750) {
            int tau = i / 1875, rem = i - tau * 1875;
            int tp = rem % 25, jq = rem / 25;
            const float* s = X + (bp0 + tau) * 15000 + jq * 200 + tp * 2;
            float2 v0 = *(const float2*)(s);
            float2 v1 = *(const float2*)(s + 50);
            float2 v2 = *(const float2*)(s + 100);
            float2 v3 = *(const float2*)(s + 150);
            char* lb = ldsb + tau * BUFSZ;
            *(unsigned*)(lb + (tp * 2 + 1) * LROW + jq * 4) = pack4_fp8(v0.x, v1.x, v2.x, v3.x);
            *(unsigned*)(lb + (tp * 2 + 2) * LROW + jq * 4) = pack4_fp8(v0.y, v1.y, v2.y, v3.y);
        }
    }
    __syncthreads();

    f32x4 acc0[5][4], acc1[5][4];
    #pragma unroll
    for (int j = 0; j < 5; j++)
        #pragma unroll
        for (int nt = 0; nt < 4; nt++) {
            acc0[j][nt] = (f32x4){0.f, 0.f, 0.f, 0.f};
            acc1[j][nt] = (f32x4){0.f, 0.f, 0.f, 0.f};
        }

    // A-frag: tile base TB, row = nt*16 + lr, 8B at k-bytes ks*32 + lg*8
    #define LDSA(TB, nt, ks) (*(const long long*)(ldsb + (TB) + ((nt) * 16 + lr) * LROW + \
                             (ks) * 32 + lg * 8))

    #pragma unroll
    for (int ks = 0; ks < 10; ks++) {
        long long bf0, bf1, bf2, bf3, bf4;
        if (ks == 0) {
            bf0 = pf[0]; bf1 = pf[1]; bf2 = pf[2]; bf3 = pf[3]; bf4 = pf[4];
        } else {
            bf0 = *(const long long*)(Mw + (0 * 10 + ks) * 512);
            bf1 = *(const long long*)(Mw + (1 * 10 + ks) * 512);
            bf2 = *(const long long*)(Mw + (2 * 10 + ks) * 512);
            bf3 = *(const long long*)(Mw + (3 * 10 + ks) * 512);
            bf4 = *(const long long*)(Mw + (4 * 10 + ks) * 512);
        }
        #pragma unroll
        for (int nt = 0; nt < 4; nt++) {
            long long a = LDSA(0, nt, ks);
            acc0[0][nt] = __builtin_amdgcn_mfma_f32_16x16x32_fp8_fp8(a, bf0, acc0[0][nt], 0, 0, 0);
            acc0[1][nt] = __builtin_amdgcn_mfma_f32_16x16x32_fp8_fp8(a, bf1, acc0[1][nt], 0, 0, 0);
            acc0[2][nt] = __builtin_amdgcn_mfma_f32_16x16x32_fp8_fp8(a, bf2, acc0[2][nt], 0, 0, 0);
            acc0[3][nt] = __builtin_amdgcn_mfma_f32_16x16x32_fp8_fp8(a, bf3, acc0[3][nt], 0, 0, 0);
            acc0[4][nt] = __builtin_amdgcn_mfma_f32_16x16x32_fp8_fp8(a, bf4, acc0[4][nt], 0, 0, 0);
        }
        #pragma unroll
        for (int nt = 0; nt < 4; nt++) {
            long long a = LDSA(BUFSZ, nt, ks);
            acc1[0][nt] = __builtin_amdgcn_mfma_f32_16x16x32_fp8_fp8(a, bf0, acc1[0][nt], 0, 0, 0);
            acc1[1][nt] = __builtin_amdgcn_mfma_f32_16x16x32_fp8_fp8(a, bf1, acc1[1][nt], 0, 0, 0);
            acc1[2][nt] = __builtin_amdgcn_mfma_f32_16x16x32_fp8_fp8(a, bf2, acc1[2][nt], 0, 0, 0);
            acc1[3][nt] = __builtin_amdgcn_mfma_f32_16x16x32_fp8_fp8(a, bf3, acc1[3][nt], 0, 0, 0);
            acc1[4][nt] = __builtin_amdgcn_mfma_f32_16x16x32_fp8_fp8(a, bf4, acc1[4][nt], 0, 0, 0);
        }
    }
    #undef LDSA

    // ---- epilogue: col m = mhalf*320 + g*80 + j*16 + lr, ext-col n = nt*16 + lg*4 + q ----
#define EPILOGUE(ACC, BP) { \
    const int b_ = (BP) >> 6, p_ = (BP) & 63; \
    const int gr_ = p_ >> 3, gc_ = p_ & 7; \
    _Pragma("unroll") \
    for (int j = 0; j < 5; j++) { \
        int colm = mhalf * 320 + g * 80 + j * 16 + lr; \
        if (colm < 256) { \
            int base = b_ * 819200 + ((gr_ * 16 + (colm >> 4)) * 128 + gc_ * 16 + (colm & 15)) * 50; \
            _Pragma("unroll") \
            for (int nt = 0; nt < 4; nt++) { \
                int t0 = nt * 16 + lg * 4; \
                if (t0 == 0) { \
                    out[base + 0] = ACC[j][0][1]; \
                    out[base + 1] = ACC[j][0][2]; \
                    out[base + 2] = ACC[j][0][3]; \
                } else if (t0 <= 46) { \
                    f32x4 v = ACC[j][nt]; \
                    __builtin_memcpy(&out[base + t0 - 1], &v, 16); \
                } else if (t0 == 48) { \
                    out[base + 47] = ACC[j][nt][0]; \
                    out[base + 48] = ACC[j][nt][1]; \
                    out[base + 49] = ACC[j][nt][2]; \
                } \
            } \
        } else if (colm < 556) { \
            int base = OFF_PRED + ((BP) * 300 + (colm - 256)) * 50; \
            _Pragma("unroll") \
            for (int nt = 0; nt < 4; nt++) { \
                int t0 = nt * 16 + lg * 4; \
                if (t0 <= 46) { \
                    f32x4 v = ACC[j][nt]; \
                    __builtin_memcpy(&out[base + t0], &v, 16); \
                } else if (t0 == 48) { \
                    out[base + 48] = ACC[j][nt][0]; \
                    out[base + 49] = ACC[j][nt][1]; \
                } \
            } \
        } \
    } }

    EPILOGUE(acc0, bp0);
    EPILOGUE(acc1, bp0 + 1);
#undef EPILOGUE
}

extern "C" void kernel_launch(void* const* d_in, const int* in_sizes, int n_in,
                              void* d_out, int out_size, void* d_ws, size_t ws_size,
                              hipStream_t stream) {
    const float* X  = (const float*)d_in[0];
    const float* U  = (const float*)d_in[1];
    const float* x0 = (const float*)d_in[2];
    const float* A  = (const float*)d_in[3];
    const float* B  = (const float*)d_in[4];
    const float* C  = (const float*)d_in[5];
    float* out = (float*)d_out;
    unsigned* M = (unsigned*)d_ws;      // 640*320 fp8 = 204,800 B (fragment-ordered)

    build_M<<<200, 256, 0, stream>>>(A, C, M);
    gemm_main<<<2048 + 1875, 256, 0, stream>>>(X, x0, (const char*)M, U, B, out);
}